// Round 4
// baseline (1301.137 us; speedup 1.0000x reference)
//
#include <hip/hip_runtime.h>
#include <stdint.h>

typedef unsigned short u16;
typedef __attribute__((ext_vector_type(8))) short bf16x8;       // 8 bf16 = 4 VGPR (MFMA A/B frag)
typedef __attribute__((ext_vector_type(4))) float f32x4;        // MFMA C/D frag
typedef __attribute__((ext_vector_type(8))) unsigned short us8; // 16B bf16 store
typedef __attribute__((ext_vector_type(4))) float fvec4;

#define BATCH 2
#define SEQ   2048
#define DIMM  2048
#define NH    16
#define DH    128
#define ROWS  (BATCH*SEQ)   // 4096
#define QKVN  (DIMM + DH)   // 2176
#define FFH   8192          // FF_MULT*DIM
#define LOG2E 1.44269504088896340736f

static __device__ __forceinline__ u16 f2bf(float x) {
  union { float f; uint32_t u; } v; v.f = x;
  uint32_t r = (v.u + 0x7fffu + ((v.u >> 16) & 1u)) >> 16;
  return (u16)r;
}

static __device__ __forceinline__ float fast_exp2(float x) {
  float r; asm("v_exp_f32 %0, %1" : "=v"(r) : "v"(x)); return r;
}

// async 16B global->LDS (dest = wave-uniform base + lane*16)
static __device__ __forceinline__ void gld_lds16(const void* g, void* l) {
  __builtin_amdgcn_global_load_lds(
      (const __attribute__((address_space(1))) uint32_t*)g,
      (__attribute__((address_space(3))) uint32_t*)l, 16, 0, 0);
}

// inline-asm LDS read: compiler does NOT track lgkm for this -> no auto-drain
// before s_barrier. Consumer must do s_waitcnt lgkmcnt(0) + sched_barrier(0).
static __device__ __forceinline__ bf16x8 ds_read16(const u16* p) {
  bf16x8 r;
  asm volatile("ds_read_b128 %0, %1"
               : "=v"(r) : "v"((uint32_t)(uintptr_t)p));
  return r;
}

// ---------------- RMSNorm: x fp32 -> xn bf16 ----------------
__global__ __launch_bounds__(256)
void rmsnorm_k(const float* __restrict__ x, const float* __restrict__ g, u16* __restrict__ xn) {
  const int row = blockIdx.x;
  const float* xr = x + (size_t)row * DIMM;
  const int off = threadIdx.x * 8;
  fvec4 a = *(const fvec4*)(xr + off);
  fvec4 b = *(const fvec4*)(xr + off + 4);
  float ss = a[0]*a[0]+a[1]*a[1]+a[2]*a[2]+a[3]*a[3]
           + b[0]*b[0]+b[1]*b[1]+b[2]*b[2]+b[3]*b[3];
  #pragma unroll
  for (int m = 32; m >= 1; m >>= 1) ss += __shfl_xor(ss, m);
  __shared__ float red[4];
  if ((threadIdx.x & 63) == 0) red[threadIdx.x >> 6] = ss;
  __syncthreads();
  float tot = red[0] + red[1] + red[2] + red[3];
  float inv = 1.0f / fmaxf(sqrtf(tot * (1.0f / DIMM)), 1e-8f);
  fvec4 ga = *(const fvec4*)(g + off);
  fvec4 gb = *(const fvec4*)(g + off + 4);
  us8 o;
  #pragma unroll
  for (int i = 0; i < 4; i++) { o[i] = f2bf(a[i]*inv*ga[i]); o[4+i] = f2bf(b[i]*inv*gb[i]); }
  *(us8*)(xn + (size_t)row * DIMM + off) = o;
}

// ---------------- transpose (+cast to bf16): in R x C -> out C x R ----------------
template<typename TIN>
__global__ __launch_bounds__(256)
void transpose_to_bf16(const TIN* __restrict__ in, u16* __restrict__ out, int R, int C) {
  __shared__ u16 tile[64 * 65];
  const int r0 = blockIdx.y * 64, c0 = blockIdx.x * 64;
  const int tr = threadIdx.x >> 2;
  const int tc = (threadIdx.x & 3) * 16;
  const TIN* ip = in + (size_t)(r0 + tr) * C + c0 + tc;
  u16 tmp[16];
  #pragma unroll
  for (int i = 0; i < 16; i++) {
    if constexpr (sizeof(TIN) == 4) tmp[i] = f2bf(((const float*)ip)[i]);
    else                            tmp[i] = ((const u16*)ip)[i];
  }
  #pragma unroll
  for (int i = 0; i < 16; i++) tile[tr * 65 + tc + i] = tmp[i];
  __syncthreads();
  const int oc  = c0 + tr;
  const int orr = (threadIdx.x & 3) * 16;
  us8 v0, v1;
  #pragma unroll
  for (int i = 0; i < 8; i++) v0[i] = tile[(orr + i) * 65 + tr];
  #pragma unroll
  for (int i = 0; i < 8; i++) v1[i] = tile[(orr + 8 + i) * 65 + tr];
  u16* op = out + (size_t)oc * R + r0 + orr;
  *(us8*)op = v0;
  *(us8*)(op + 8) = v1;
}

// ---------------- generic 128x128 bf16 GEMM, BK=32 (qkv + attn-out) ----------------
template<int MODE>
__global__ __launch_bounds__(256, 2)
void gemm_bf16(const u16* __restrict__ A, const u16* __restrict__ BT, int K,
               float* __restrict__ outF, u16* __restrict__ outQ, u16* __restrict__ outKV,
               const float* __restrict__ tmpF) {
  __shared__ __align__(16) u16 lA[128 * 32];
  __shared__ __align__(16) u16 lB[128 * 32];
  const int tid = threadIdx.x;
  const int wave = tid >> 6, lane = tid & 63;
  const int lid = lane & 15, quad = lane >> 4;
  const int wm = wave >> 1, wn = wave & 1;
  const int row0 = blockIdx.y * 128;
  const int col0 = blockIdx.x * 128;
  f32x4 acc[4][4];
  #pragma unroll
  for (int i = 0; i < 4; i++)
    #pragma unroll
    for (int j = 0; j < 4; j++) { acc[i][j][0]=0.f; acc[i][j][1]=0.f; acc[i][j][2]=0.f; acc[i][j][3]=0.f; }

  const int rA0 = wave * 32;
  const int rsub = lane >> 2;
  const int cl = lane & 3;

  for (int k0 = 0; k0 < K; k0 += 32) {
    #pragma unroll
    for (int h2 = 0; h2 < 2; ++h2) {
      int rloc = rA0 + h2 * 16 + rsub;
      int gc = cl ^ ((rloc >> 1) & 3);
      gld_lds16(A  + (size_t)(row0 + rloc) * K + k0 + gc * 8, lA + (rA0 + h2 * 16) * 32);
      gld_lds16(BT + (size_t)(col0 + rloc) * K + k0 + gc * 8, lB + (rA0 + h2 * 16) * 32);
    }
    __syncthreads();
    bf16x8 af[4], bfr[4];
    #pragma unroll
    for (int i = 0; i < 4; i++) {
      int r  = wm * 64 + i * 16 + lid;
      af[i]  = *(const bf16x8*)(lA + r * 32 + (quad ^ ((r >> 1) & 3)) * 8);
      int rb = wn * 64 + i * 16 + lid;
      bfr[i] = *(const bf16x8*)(lB + rb * 32 + (quad ^ ((rb >> 1) & 3)) * 8);
    }
    #pragma unroll
    for (int im = 0; im < 4; im++)
      #pragma unroll
      for (int in = 0; in < 4; in++)
        acc[im][in] = __builtin_amdgcn_mfma_f32_16x16x32_bf16(af[im], bfr[in], acc[im][in], 0, 0, 0);
    __syncthreads();
  }

  #pragma unroll
  for (int im = 0; im < 4; im++)
    #pragma unroll
    for (int in = 0; in < 4; in++) {
      int col = col0 + wn * 64 + in * 16 + lid;
      int rbase = row0 + wm * 64 + im * 16 + quad * 4;
      #pragma unroll
      for (int rg = 0; rg < 4; rg++) {
        float v = acc[im][in][rg];
        int row = rbase + rg;
        if constexpr (MODE == 0) {
          if (col < DIMM) outQ[(size_t)row * DIMM + col] = f2bf(v);
          else            outKV[(size_t)row * DH + (col - DIMM)] = f2bf(v);
        } else if constexpr (MODE == 2) {
          outF[(size_t)row * DIMM + col] = v;
        } else {
          size_t idx = (size_t)row * DIMM + col;
          outF[idx] += v + tmpF[idx];
        }
      }
    }
}

// ================= shared 8-phase 256-row GEMM machinery =================
// R4: frag loads are inline-asm ds_read_b128 (untracked lgkm) so the compiler
// cannot auto-drain them before s_barrier. Each quad16 is preceded by an
// explicit s_waitcnt lgkmcnt(0) + sched_barrier(0) (rule #18). At each quad16
// the wave's pending LDS reads are exactly the frags that cluster consumes.
// Schedule/barriers/vmcnt ring identical to the verified R3 version.
static __device__ __forceinline__ void stage_half(const u16* __restrict__ src, u16* dst,
                                                  int K, int sr, int sgc, int wave) {
  gld_lds16(src + (size_t)sr * K + sgc,       dst + wave * 1024);
  gld_lds16(src + (size_t)(sr + 8) * K + sgc, dst + wave * 1024 + 512);
}

static __device__ __forceinline__ void lda4(bf16x8 (&dst)[4][2], const u16* sAb,
                                            int mh, int wm, int lid, int c0) {
  #pragma unroll
  for (int i = 0; i < 4; ++i) {
    const u16* p = sAb + (mh * 128 + wm * 64 + i * 16 + lid) * 64;
    dst[i][0] = ds_read16(p + c0);
    dst[i][1] = ds_read16(p + (c0 ^ 32));
  }
}

static __device__ __forceinline__ void ldb2(bf16x8 (&dst)[2][2], const u16* sBb,
                                            int nh, int wn, int lid, int c0) {
  #pragma unroll
  for (int n = 0; n < 2; ++n) {
    const u16* p = sBb + (nh * 128 + wn * 32 + n * 16 + lid) * 64;
    dst[n][0] = ds_read16(p + c0);
    dst[n][1] = ds_read16(p + (c0 ^ 32));
  }
}

static __device__ __forceinline__ void quad16(f32x4 (&acc)[8][4], const bf16x8 (&af)[4][2],
                                              const bf16x8 (&bf)[2][2], int mh, int nh) {
  __builtin_amdgcn_s_setprio(1);
  #pragma unroll
  for (int i = 0; i < 4; ++i)
    #pragma unroll
    for (int n = 0; n < 2; ++n) {
      f32x4 c = acc[mh * 4 + i][nh * 2 + n];
      c = __builtin_amdgcn_mfma_f32_16x16x32_bf16(af[i][0], bf[n][0], c, 0, 0, 0);
      c = __builtin_amdgcn_mfma_f32_16x16x32_bf16(af[i][1], bf[n][1], c, 0, 0, 0);
      acc[mh * 4 + i][nh * 2 + n] = c;
    }
  __builtin_amdgcn_s_setprio(0);
}

#define VMW(n) asm volatile("s_waitcnt vmcnt(" #n ")" ::: "memory")
#define BAR8() __builtin_amdgcn_s_barrier()
#define LGKM0() do { asm volatile("s_waitcnt lgkmcnt(0)" ::: "memory"); \
                     __builtin_amdgcn_sched_barrier(0); } while (0)

// Stage issue ring per iter (2 loads each): P1:S1=b1.A1(kt1) P2:S2=b0.A0(kt2)
// P3:S3=b0.B0 P4:S4=b0.B1 P5:S5=b0.A1 P6:S6=b1.A0(kt3) P7:S7=b1.B0 P8:S8=b1.B1.
// Post-MFMA reads: P1:B1(T0)<-S4(prev) P2:A1(T0)<-S5(prev) P4:B0,A0(T1)<-S7,S6(prev)
// P5:B1(T1)<-S8(prev) P6:A1(T1)<-S1(cur) P8:B0,A0(T0')<-S3,S2(cur).
#define EIGHT_PHASE_LOOP(NITER)                                               \
  {                                                                           \
    STAGE_A(0,0,0); STAGE_B(0,0,0); STAGE_B(0,1,0); STAGE_A(0,1,0);           \
    STAGE_A(1,0,1); STAGE_B(1,0,1); STAGE_B(1,1,1);                           \
    VMW(6);                                                                   \
    BAR8();                                                                   \
    lda4(af, sA[0], 0, wm, lid, c0);   /* A0(T0) */                           \
    ldb2(bW, sB[0], 0, wn, lid, c0);   /* B0(T0) */                           \
    for (int I = 0; I < (NITER); ++I) {                                       \
      const bool more = (I + 1 < (NITER));                                    \
      const int kt1 = 2*I+1, kt2 = 2*I+2, kt3 = 2*I+3;                        \
      /* P1: T0 q(0,0); post-read B1(T0) */                                   \
      STAGE_A(1,1,kt1);                                                       \
      BAR8();                                                                 \
      LGKM0();                                                                \
      quad16(acc, af, bW, 0, 0);                                              \
      ldb2(bX, sB[0], 1, wn, lid, c0);                                        \
      VMW(8);                                                                 \
      BAR8();                                                                 \
      /* P2: q(0,1); post-read A1(T0) */                                      \
      if (more) STAGE_A(0,0,kt2);                                             \
      BAR8();                                                                 \
      LGKM0();                                                                \
      quad16(acc, af, bX, 0, 1);                                              \
      lda4(af, sA[0], 1, wm, lid, c0);                                        \
      BAR8();                                                                 \
      /* P3: q(1,1) */                                                        \
      if (more) STAGE_B(0,0,kt2);                                             \
      BAR8();                                                                 \
      LGKM0();                                                                \
      quad16(acc, af, bX, 1, 1);                                              \
      if (more) { VMW(8); } else { VMW(4); }                                  \
      BAR8();                                                                 \
      /* P4: q(1,0); post-read B0(T1), A0(T1) */                              \
      if (more) STAGE_B(0,1,kt2);                                             \
      BAR8();                                                                 \
      LGKM0();                                                                \
      quad16(acc, af, bW, 1, 0);                                              \
      ldb2(bW, sB[1], 0, wn, lid, c0);                                        \
      lda4(af, sA[1], 0, wm, lid, c0);                                        \
      if (more) { VMW(8); } else { VMW(2); }                                  \
      BAR8();                                                                 \
      /* P5: T1 q(0,0); post-read B1(T1) */                                   \
      if (more) STAGE_A(0,1,kt2);                                             \
      BAR8();                                                                 \
      LGKM0();                                                                \
      quad16(acc, af, bW, 0, 0);                                              \
      ldb2(bX, sB[1], 1, wn, lid, c0);                                        \
      if (more) { VMW(8); } else { VMW(0); }                                  \
      BAR8();                                                                 \
      /* P6: q(0,1); post-read A1(T1) */                                      \
      if (more) STAGE_A(1,0,kt3);                                             \
      BAR8();                                                                 \
      LGKM0();                                                                \
      quad16(acc, af, bX, 0, 1);                                              \
      lda4(af, sA[1], 1, wm, lid, c0);                                        \
      BAR8();                                                                 \
      /* P7: q(1,1) */                                                        \
      if (more) STAGE_B(1,0,kt3);                                             \
      BAR8();                                                                 \
      LGKM0();                                                                \
      quad16(acc, af, bX, 1, 1);                                              \
      if (more) { VMW(8); }                                                   \
      BAR8();                                                                 \
      /* P8: q(1,0); post-read B0(T0'), A0(T0') */                            \
      if (more) STAGE_B(1,1,kt3);                                             \
      BAR8();                                                                 \
      LGKM0();                                                                \
      quad16(acc, af, bW, 1, 0);                                              \
      if (more) {                                                             \
        ldb2(bW, sB[0], 0, wn, lid, c0);                                      \
        lda4(af, sA[0], 0, wm, lid, c0);                                      \
        VMW(8);                                                               \
      }                                                                       \
      BAR8();                                                                 \
    }                                                                         \
    LGKM0();                                                                  \
  }

// ================= ff1 GEMM + SwiGLU (256x(128val+128gate), BK=64, 8-phase) =================
__global__ __launch_bounds__(512, 2)
void gemm_ff1_swiglu_8p(const u16* __restrict__ A, const u16* __restrict__ BT,
                        u16* __restrict__ FF) {
  __shared__ __align__(16) u16 sA[2][256 * 64];   // 64 KB
  __shared__ __align__(16) u16 sB[2][256 * 64];   // 64 KB
  const int tid = threadIdx.x;
  const int wave = tid >> 6, lane = tid & 63;
  const int lid = lane & 15, quad = lane >> 4;
  const int wm = wave >> 2, wn = wave & 3;
  const int K = DIMM;

  // XCD-aware swizzle: nwg = 1024, 8 XCDs, 128 blocks each (bijective)
  int orig = blockIdx.y * 64 + blockIdx.x;
  int swz = (orig & 7) * 128 + (orig >> 3);
  const int row0 = (swz >> 6) * 256;
  const int n0 = (swz & 63) * 128;

  const int sr  = wave * 16 + (lane >> 3);           // stage row within half-tile
  const int sgc = (((lane & 7) ^ (lane >> 3)) << 3); // pre-swizzled source chunk (u16)
  const int c0  = ((quad ^ (lid & 7)) << 3);         // ds_read swizzled chunk (u16)

  f32x4 acc[8][4];
  #pragma unroll
  for (int i = 0; i < 8; ++i)
    #pragma unroll
    for (int j = 0; j < 4; ++j) { acc[i][j][0]=0.f; acc[i][j][1]=0.f; acc[i][j][2]=0.f; acc[i][j][3]=0.f; }
  bf16x8 af[4][2], bW[2][2], bX[2][2];

  #define STAGE_A(b, h, kt) stage_half(A  + (size_t)(row0 + (h)*128) * K + (kt)*64, &sA[b][(h)*8192], K, sr, sgc, wave)
  #define STAGE_B(b, h, kt) stage_half(BT + (size_t)((h) ? (FFH + n0) : n0) * K + (kt)*64, &sB[b][(h)*8192], K, sr, sgc, wave)

  EIGHT_PHASE_LOOP(K / 128)

  #undef STAGE_A
  #undef STAGE_B

  // ---- epilogue: SwiGLU (val = acc[..][0..1], gate = acc[..][2..3], same output col) ----
  #pragma unroll
  for (int mi = 0; mi < 8; ++mi) {
    const int row = row0 + (mi >> 2) * 128 + wm * 64 + (mi & 3) * 16 + quad * 4;
    #pragma unroll
    for (int n = 0; n < 2; ++n) {
      const int col = n0 + wn * 32 + n * 16 + lid;
      #pragma unroll
      for (int rg = 0; rg < 4; ++rg) {
        float vv = acc[mi][n][rg];
        float gg = acc[mi][2 + n][rg];
        float sig = 1.0f / (1.0f + fast_exp2(-gg * LOG2E));
        FF[(size_t)(row + rg) * FFH + col] = f2bf(vv * gg * sig);
      }
    }
  }
}

// ================= ff2 GEMM (256x256, BK=64, 8-phase, split-K=2) =================
// Grid 8 x 16 x 2 = 256 blocks (1 round on 256 CUs). ks=0 -> out, ks=1 -> tmp;
// the attn-out GEMM epilogue adds tmp back (out += attnproj + tmp).
__global__ __launch_bounds__(512, 2)
void gemm_ff2_8p(const u16* __restrict__ A, const u16* __restrict__ BT,
                 float* __restrict__ out0, float* __restrict__ out1) {
  __shared__ __align__(16) u16 sA[2][256 * 64];
  __shared__ __align__(16) u16 sB[2][256 * 64];
  const int tid = threadIdx.x;
  const int wave = tid >> 6, lane = tid & 63;
  const int lid = lane & 15, quad = lane >> 4;
  const int wm = wave >> 2, wn = wave & 3;
  const int K = FFH;  // row stride (full K)

  // XCD swizzle over 256 blocks: 32 per XCD = 2 row-panels x 8 n-panels x 2 ks
  int orig = (blockIdx.z * 16 + blockIdx.y) * 8 + blockIdx.x;
  int swz = (orig & 7) * 32 + (orig >> 3);
  const int n0   = (swz & 7) * 256;
  const int ks   = (swz >> 3) & 1;
  const int row0 = (swz >> 4) * 256;

  const u16* Ab = A  + ks * 4096;   // K-half column offset
  const u16* Bb = BT + ks * 4096;

  const int sr  = wave * 16 + (lane >> 3);
  const int sgc = (((lane & 7) ^ (lane >> 3)) << 3);
  const int c0  = ((quad ^ (lid & 7)) << 3);

  f32x4 acc[8][4];
  #pragma unroll
  for (int i = 0; i < 8; ++i)
    #pragma unroll
    for (int j = 0; j < 4; ++j) { acc[i][j][0]=0.f; acc[i][j][1]=0.f; acc[i][j][2]=0.f; acc[i][j][3]=0.f; }
  bf16x8 af[4][2], bW[2][2], bX[2][2];

  #define STAGE_A(b, h, kt) stage_half(Ab + (size_t)(row0 + (h)*128) * K + (kt)*64, &sA[b][(h)*8192], K, sr, sgc, wave)
  #define STAGE_B(b, h, kt) stage_half(Bb + (size_t)(n0 + (h)*128) * K + (kt)*64,  &sB[b][(h)*8192], K, sr, sgc, wave)

  EIGHT_PHASE_LOOP(32)   // K-half 4096 / 128

  #undef STAGE_A
  #undef STAGE_B

  float* dst = ks ? out1 : out0;
  #pragma unroll
  for (int mi = 0; mi < 8; ++mi) {
    const int row = row0 + (mi >> 2) * 128 + wm * 64 + (mi & 3) * 16 + quad * 4;
    #pragma unroll
    for (int j = 0; j < 4; ++j) {
      const int col = n0 + (j >> 1) * 128 + wn * 32 + (j & 1) * 16 + lid;
      #pragma unroll
      for (int rg = 0; rg < 4; ++rg)
        dst[(size_t)(row + rg) * DIMM + col] = acc[mi][j][rg];
    }
  }
}

// ---------------- flash attention v2 (unchanged) ----------------
__global__ __launch_bounds__(256, 1)
void attn_k2(const u16* __restrict__ qws, const u16* __restrict__ kvws,
             const u16* __restrict__ kvt, u16* __restrict__ attnws) {
  __shared__ __align__(16) u16 kvls[128 * 128];   // 32 KB
  __shared__ __align__(16) u16 kvtls[128 * 128];  // 32 KB
  __shared__ __align__(16) u16 plds[4][32][136];  // 34 KB
  const int tid = threadIdx.x;
  const int wave = tid >> 6, lane = tid & 63;
  const int lid = lane & 15, quad = lane >> 4;
  const int hb = blockIdx.y;
  const int h = hb & (NH - 1), b = hb >> 4;
  const int pair = blockIdx.x;                     // 0..7
  const float slope2 = fast_exp2(-0.5f * (float)(h + 1)) * LOG2E;
  const float scale2 = 0.08838834764831845f * LOG2E;
  const float NEG = -__builtin_inff();

  const u16* kvb  = kvws + (size_t)b * SEQ * DH;
  const u16* kvtb = kvt  + (size_t)b * DH * SEQ;

  #pragma unroll 1
  for (int tt = 0; tt < 2; tt++) {
    const int T = tt ? (15 - pair) : pair;
    const int rw = T * 128 + wave * 32;

    bf16x8 qf[2][4];
    #pragma unroll
    for (int ig = 0; ig < 2; ig++)
      #pragma unroll
      for (int ks = 0; ks < 4; ks++)
        qf[ig][ks] = *(const bf16x8*)(qws + (size_t)(b * SEQ + rw + ig * 16 + lid) * DIMM
                                       + h * DH + ks * 32 + quad * 8);
    float srow2[2][4];
    #pragma unroll
    for (int ig = 0; ig < 2; ig++)
      #pragma unroll
      for (int rg = 0; rg < 4; rg++)
        srow2[ig][rg] = slope2 * (float)(rw + ig * 16 + quad * 4 + rg);

    f32x4 o[2][8];
    #pragma unroll
    for (int ig = 0; ig < 2; ig++)
      #pragma unroll
      for (int nd = 0; nd < 8; nd++) { o[ig][nd][0]=0.f; o[ig][nd][1]=0.f; o[ig][nd][2]=0.f; o[ig][nd][3]=0.f; }
    float m2[2][4], l[2][4];
    #pragma unroll
    for (int ig = 0; ig < 2; ig++)
      #pragma unroll
      for (int rg = 0; rg < 4; rg++) { m2[ig][rg] = NEG; l[ig][rg] = 0.f; }

    const int njt = T + 1;
    #pragma unroll 1
    for (int jt = 0; jt < njt; jt++) {
      const int j0 = jt * 128;
      __syncthreads();
      {
        const int c = lane & 15;
        const int r4 = lane >> 4;
        #pragma unroll
        for (int it = 0; it < 8; it++) {
          const int r = wave * 32 + it * 4 + r4;
          const int gc = c ^ (r & 15);
          gld_lds16(kvb  + (size_t)(j0 + r) * DH + gc * 8,        kvls  + (wave * 32 + it * 4) * 128);
          gld_lds16(kvtb + (size_t)r * SEQ + j0 + gc * 8,         kvtls + (wave * 32 + it * 4) * 128);
        }
      }
      __syncthreads();

      const int rhi = rw + 31;
      const int nbmax = min(8, ((rhi - j0) >> 4) + 1);
      const int ks2max = (nbmax + 1) >> 1;

      float pvv[2][8][4];
      float mt[2][4];
      #pragma unroll
      for (int ig = 0; ig < 2; ig++)
        #pragma unroll
        for (int rg = 0; rg < 4; rg++) mt[ig][rg] = NEG;

      #pragma unroll
      for (int nb = 0; nb < 8; nb++) {
        if (nb < nbmax) {
          bf16x8 bk[4];
          #pragma unroll
          for (int ks = 0; ks < 4; ks++)
            bk[ks] = *(const bf16x8*)(kvls + (nb * 16 + lid) * 128 + (((ks * 4 + quad) ^ lid) << 3));
          f32x4 s0, s1;
          s0[0]=0.f;s0[1]=0.f;s0[2]=0.f;s0[3]=0.f;
          s1[0]=0.f;s1[1]=0.f;s1[2]=0.f;s1[3]=0.f;
          #pragma unroll
          for (int ks = 0; ks < 4; ks++) {
            s0 = __builtin_amdgcn_mfma_f32_16x16x32_bf16(qf[0][ks], bk[ks], s0, 0, 0, 0);
            s1 = __builtin_amdgcn_mfma_f32_16x16x32_bf16(qf[1][ks], bk[ks], s1, 0, 0, 0);
          }
          const int jl = j0 + nb * 16 + lid;
          const float sj = slope2 * (float)jl;
          #pragma unroll
          for (int rg = 0; rg < 4; rg++) {
            const int row0r = rw + quad * 4 + rg;
            float e0 = fmaf(s0[rg], scale2, sj) - srow2[0][rg];
            e0 = (jl <= row0r) ? e0 : NEG;
            pvv[0][nb][rg] = e0;
            mt[0][rg] = fmaxf(mt[0][rg], e0);
            float e1 = fmaf(s1[rg], scale2, sj) - srow2[1][rg];
            e1 = (jl <= row0r + 16) ? e1 : NEG;
            pvv[1][nb][rg] = e1;
            mt[1][rg] = fmaxf(mt[1][rg], e1);
          }
        }
      }

      float alpha[2][4];
      #pragma unroll
      for (int ig = 0; ig < 2; ig++)
        #pragma unroll
        for (int rg = 0; rg < 4; rg++) {
          float m = mt[ig][rg];
          m = fmaxf(m, __shfl_xor(m, 1));
          m = fmaxf(m, __shfl_xor(m, 2));
          m = fmaxf(m, __shfl_xor(m, 4));
          m = fmaxf(m, __shfl_xor(m, 8));
          float mn = fmaxf(m2[ig][rg], m);
          alpha[ig][rg] = fast_exp2(m2[ig][rg] - mn);
          m2[ig][rg] = mn;
        }

      float rs[2][4];
      #pragma unroll
      for (int ig = 0; ig < 2; ig++)
        #pragma unroll
        for (int rg = 0; rg < 4; rg++) rs[ig][rg] = 0.f;
      #pragma unroll
      for (int nb = 0; nb < 8; nb++) {
        if (nb < nbmax) {
          #pragma unroll
          for (int ig = 0; ig < 2; ig++)
            #pragma unroll
            for (int rg = 0; rg < 4; rg++) {
              float p = fast_exp2(pvv[ig][nb][rg] - m2[ig][rg]);
              rs[ig][rg] += p;
              plds[wave][ig * 16 + quad * 4 + rg][nb * 16 + lid] = f2bf(p);
            }
        }
      }
      if (nbmax & 1) {
        #pragma unroll
        for (int ig = 0; ig < 2; ig++)
          #pragma unroll
          for (int rg = 0; rg < 4; rg++)
            plds[wave][ig * 16 + quad * 4 + rg][nbmax * 16 + lid] = 0;
      }

      #pragma unroll
      for (int ig = 0; ig < 2; ig++)
        #pragma unroll
        for (int rg = 0; rg < 4; rg++) {
          float r = rs[ig][rg];
          r += __shfl_xor(r, 1);
          r += __shfl_xor(r, 2);
          r += __shfl_xor(r, 4);
          r += __shfl_xor(r, 8);
          l[ig][rg] = l[ig][rg] * alpha[ig][rg] + r;
        }
      #pragma unroll
      for (int ig = 0; ig < 2; ig++)
        #pragma unroll
        for (int nd = 0; nd < 8; nd++)
          #pragma unroll
          for (int rg = 0; rg < 4; rg++) o[ig][nd][rg] *= alpha[ig][rg];

      asm volatile("s_waitcnt lgkmcnt(0)" ::: "memory");
      #pragma unroll
      for (int ks2 = 0; ks2 < 4; ks2++) {
        if (ks2 < ks2max) {
          bf16x8 pa0 = *(const bf16x8*)&plds[wave][lid][ks2 * 32 + quad * 8];
          bf16x8 pa1 = *(const bf16x8*)&plds[wave][16 + lid][ks2 * 32 + quad * 8];
          #pragma unroll
          for (int nd = 0; nd < 8; nd++) {
            bf16x8 bv = *(const bf16x8*)(kvtls + (nd * 16 + lid) * 128 + (((ks2 * 4 + quad) ^ lid) << 3));
            o[0][nd] = __builtin_amdgcn_mfma_f32_16x16x32_bf16(pa0, bv, o[0][nd], 0, 0, 0);
            o[1][nd] = __builtin_amdgcn_mfma_f32_16x16x32_bf16(pa1, bv, o[1][nd], 0, 0, 0);
          }
        }
      }
    } // jt

    #pragma unroll
    for (int ig = 0; ig < 2; ig++) {
      float inv[4];
      #pragma unroll
      for (int rg = 0; rg < 4; rg++) inv[rg] = 1.0f / l[ig][rg];
      #pragma unroll
      for (int nd = 0; nd < 8; nd++)
        #pragma unroll
        for (int rg = 0; rg < 4; rg++) {
          int row = rw + ig * 16 + quad * 4 + rg;
          attnws[(size_t)(b * SEQ + row) * DIMM + h * DH + nd * 16 + lid] =
              f2bf(o[ig][nd][rg] * inv[rg]);
        }
    }
  } // tt
}

// ---------------- launcher ----------------
extern "C" void kernel_launch(void* const* d_in, const int* in_sizes, int n_in,
                              void* d_out, int out_size, void* d_ws, size_t ws_size,
                              hipStream_t stream) {
  (void)in_sizes; (void)n_in; (void)out_size; (void)ws_size;
  const float* x     = (const float*)d_in[0];
  const float* g     = (const float*)d_in[1];
  const float* w_qkv = (const float*)d_in[2];
  const float* w_ao  = (const float*)d_in[3];
  const float* w_ff1 = (const float*)d_in[4];
  const float* w_ff2 = (const float*)d_in[5];
  float* out = (float*)d_out;

  u16* ws = (u16*)d_ws;
  u16* xn     = ws;                   // 4096x2048
  u16* wTqkv  = xn     + 8388608;     // 2176x2048
  u16* wTattn = wTqkv  + 4456448;     // 2048x2048
  u16* wTff1  = wTattn + 4194304;     // 16384x2048
  u16* wTff2  = wTff1  + 33554432;    // 2048x8192
  u16* ffin   = wTff2  + 16777216;    // 4096x8192
  u16* qws    = ffin   + 33554432;    // 4096x2048
  u16* kvws   = qws    + 8388608;     // 4096x128
  u16* kvtws  = kvws   + 524288;      // 2 x (128x2048)
  u16* attnws = kvtws  + 524288;      // 4096x2048
  float* tmpf = (float*)wTff1;        // 4096x2048 fp32 (dead after ff1, 64MB region)

  transpose_to_bf16<float><<<dim3(QKVN/64, DIMM/64), 256, 0, stream>>>(w_qkv, wTqkv, DIMM, QKVN);
  transpose_to_bf16<float><<<dim3(DIMM/64, DIMM/64), 256, 0, stream>>>(w_ao, wTattn, DIMM, DIMM);
  transpose_to_bf16<float><<<dim3((2*FFH)/64, DIMM/64), 256, 0, stream>>>(w_ff1, wTff1, DIMM, 2*FFH);
  transpose_to_bf16<float><<<dim3(DIMM/64, FFH/64), 256, 0, stream>>>(w_ff2, wTff2, FFH, DIMM);

  rmsnorm_k<<<ROWS, 256, 0, stream>>>(x, g, xn);

  gemm_bf16<0><<<dim3(QKVN/128, ROWS/128), 256, 0, stream>>>(xn, wTqkv, DIMM, nullptr, qws, kvws, nullptr);

  transpose_to_bf16<u16><<<dim3(DH/64, SEQ/64), 256, 0, stream>>>(kvws, kvtws, SEQ, DH);
  transpose_to_bf16<u16><<<dim3(DH/64, SEQ/64), 256, 0, stream>>>(kvws + (size_t)SEQ*DH, kvtws + (size_t)DH*SEQ, SEQ, DH);

  attn_k2<<<dim3(8, NH*BATCH), 256, 0, stream>>>(qws, kvws, kvtws, attnws);

  gemm_ff1_swiglu_8p<<<dim3(FFH/128, ROWS/256), 512, 0, stream>>>(xn, wTff1, ffin);
  gemm_ff2_8p<<<dim3(8, 16, 2), 512, 0, stream>>>(ffin, wTff2, out, tmpf);

  gemm_bf16<3><<<dim3(DIMM/128, ROWS/128), 256, 0, stream>>>(attnws, wTattn, DIMM, out, nullptr, nullptr, tmpf);
}

// Round 5
// 908.033 us; speedup vs baseline: 1.4329x; 1.4329x over previous
//
#include <hip/hip_runtime.h>
#include <stdint.h>

typedef unsigned short u16;
typedef __attribute__((ext_vector_type(8))) short bf16x8;       // 8 bf16 = 4 VGPR (MFMA A/B frag)
typedef __attribute__((ext_vector_type(4))) float f32x4;        // MFMA C/D frag
typedef __attribute__((ext_vector_type(8))) unsigned short us8; // 16B bf16 store
typedef __attribute__((ext_vector_type(4))) float fvec4;

#define BATCH 2
#define SEQ   2048
#define DIMM  2048
#define NH    16
#define DH    128
#define ROWS  (BATCH*SEQ)   // 4096
#define QKVN  (DIMM + DH)   // 2176
#define FFH   8192          // FF_MULT*DIM
#define LOG2E 1.44269504088896340736f

static __device__ __forceinline__ u16 f2bf(float x) {
  union { float f; uint32_t u; } v; v.f = x;
  uint32_t r = (v.u + 0x7fffu + ((v.u >> 16) & 1u)) >> 16;
  return (u16)r;
}

static __device__ __forceinline__ float fast_exp2(float x) {
  float r; asm("v_exp_f32 %0, %1" : "=v"(r) : "v"(x)); return r;
}

// async 16B global->LDS (dest = wave-uniform base + lane*16)
static __device__ __forceinline__ void gld_lds16(const void* g, void* l) {
  __builtin_amdgcn_global_load_lds(
      (const __attribute__((address_space(1))) uint32_t*)g,
      (__attribute__((address_space(3))) uint32_t*)l, 16, 0, 0);
}

// ---------------- RMSNorm: x fp32 -> xn bf16 ----------------
__global__ __launch_bounds__(256)
void rmsnorm_k(const float* __restrict__ x, const float* __restrict__ g, u16* __restrict__ xn) {
  const int row = blockIdx.x;
  const float* xr = x + (size_t)row * DIMM;
  const int off = threadIdx.x * 8;
  fvec4 a = *(const fvec4*)(xr + off);
  fvec4 b = *(const fvec4*)(xr + off + 4);
  float ss = a[0]*a[0]+a[1]*a[1]+a[2]*a[2]+a[3]*a[3]
           + b[0]*b[0]+b[1]*b[1]+b[2]*b[2]+b[3]*b[3];
  #pragma unroll
  for (int m = 32; m >= 1; m >>= 1) ss += __shfl_xor(ss, m);
  __shared__ float red[4];
  if ((threadIdx.x & 63) == 0) red[threadIdx.x >> 6] = ss;
  __syncthreads();
  float tot = red[0] + red[1] + red[2] + red[3];
  float inv = 1.0f / fmaxf(sqrtf(tot * (1.0f / DIMM)), 1e-8f);
  fvec4 ga = *(const fvec4*)(g + off);
  fvec4 gb = *(const fvec4*)(g + off + 4);
  us8 o;
  #pragma unroll
  for (int i = 0; i < 4; i++) { o[i] = f2bf(a[i]*inv*ga[i]); o[4+i] = f2bf(b[i]*inv*gb[i]); }
  *(us8*)(xn + (size_t)row * DIMM + off) = o;
}

// ---------------- transpose (+cast to bf16): in R x C -> out C x R ----------------
template<typename TIN>
__global__ __launch_bounds__(256)
void transpose_to_bf16(const TIN* __restrict__ in, u16* __restrict__ out, int R, int C) {
  __shared__ u16 tile[64 * 65];
  const int r0 = blockIdx.y * 64, c0 = blockIdx.x * 64;
  const int tr = threadIdx.x >> 2;
  const int tc = (threadIdx.x & 3) * 16;
  const TIN* ip = in + (size_t)(r0 + tr) * C + c0 + tc;
  u16 tmp[16];
  #pragma unroll
  for (int i = 0; i < 16; i++) {
    if constexpr (sizeof(TIN) == 4) tmp[i] = f2bf(((const float*)ip)[i]);
    else                            tmp[i] = ((const u16*)ip)[i];
  }
  #pragma unroll
  for (int i = 0; i < 16; i++) tile[tr * 65 + tc + i] = tmp[i];
  __syncthreads();
  const int oc  = c0 + tr;
  const int orr = (threadIdx.x & 3) * 16;
  us8 v0, v1;
  #pragma unroll
  for (int i = 0; i < 8; i++) v0[i] = tile[(orr + i) * 65 + tr];
  #pragma unroll
  for (int i = 0; i < 8; i++) v1[i] = tile[(orr + 8 + i) * 65 + tr];
  u16* op = out + (size_t)oc * R + r0 + orr;
  *(us8*)op = v0;
  *(us8*)(op + 8) = v1;
}

// ---------------- generic 128x128 bf16 GEMM, BK=32 (qkv + attn-out) ----------------
template<int MODE>
__global__ __launch_bounds__(256, 2)
void gemm_bf16(const u16* __restrict__ A, const u16* __restrict__ BT, int K,
               float* __restrict__ outF, u16* __restrict__ outQ, u16* __restrict__ outKV,
               const float* __restrict__ tmpF) {
  __shared__ __align__(16) u16 lA[128 * 32];
  __shared__ __align__(16) u16 lB[128 * 32];
  const int tid = threadIdx.x;
  const int wave = tid >> 6, lane = tid & 63;
  const int lid = lane & 15, quad = lane >> 4;
  const int wm = wave >> 1, wn = wave & 1;
  const int row0 = blockIdx.y * 128;
  const int col0 = blockIdx.x * 128;
  f32x4 acc[4][4];
  #pragma unroll
  for (int i = 0; i < 4; i++)
    #pragma unroll
    for (int j = 0; j < 4; j++) { acc[i][j][0]=0.f; acc[i][j][1]=0.f; acc[i][j][2]=0.f; acc[i][j][3]=0.f; }

  const int rA0 = wave * 32;
  const int rsub = lane >> 2;
  const int cl = lane & 3;

  for (int k0 = 0; k0 < K; k0 += 32) {
    #pragma unroll
    for (int h2 = 0; h2 < 2; ++h2) {
      int rloc = rA0 + h2 * 16 + rsub;
      int gc = cl ^ ((rloc >> 1) & 3);
      gld_lds16(A  + (size_t)(row0 + rloc) * K + k0 + gc * 8, lA + (rA0 + h2 * 16) * 32);
      gld_lds16(BT + (size_t)(col0 + rloc) * K + k0 + gc * 8, lB + (rA0 + h2 * 16) * 32);
    }
    __syncthreads();
    bf16x8 af[4], bfr[4];
    #pragma unroll
    for (int i = 0; i < 4; i++) {
      int r  = wm * 64 + i * 16 + lid;
      af[i]  = *(const bf16x8*)(lA + r * 32 + (quad ^ ((r >> 1) & 3)) * 8);
      int rb = wn * 64 + i * 16 + lid;
      bfr[i] = *(const bf16x8*)(lB + rb * 32 + (quad ^ ((rb >> 1) & 3)) * 8);
    }
    #pragma unroll
    for (int im = 0; im < 4; im++)
      #pragma unroll
      for (int in = 0; in < 4; in++)
        acc[im][in] = __builtin_amdgcn_mfma_f32_16x16x32_bf16(af[im], bfr[in], acc[im][in], 0, 0, 0);
    __syncthreads();
  }

  #pragma unroll
  for (int im = 0; im < 4; im++)
    #pragma unroll
    for (int in = 0; in < 4; in++) {
      int col = col0 + wn * 64 + in * 16 + lid;
      int rbase = row0 + wm * 64 + im * 16 + quad * 4;
      #pragma unroll
      for (int rg = 0; rg < 4; rg++) {
        float v = acc[im][in][rg];
        int row = rbase + rg;
        if constexpr (MODE == 0) {
          if (col < DIMM) outQ[(size_t)row * DIMM + col] = f2bf(v);
          else            outKV[(size_t)row * DH + (col - DIMM)] = f2bf(v);
        } else if constexpr (MODE == 2) {
          outF[(size_t)row * DIMM + col] = v;
        } else {
          size_t idx = (size_t)row * DIMM + col;
          outF[idx] += v + tmpF[idx];
        }
      }
    }
}

// ================= shared 8-phase 256-row GEMM machinery (R3-verified) =================
// 512 threads = 8 waves (2M x 4N). Per-wave C: 128x64. LDS 128 KiB, fixed-role
// double buffer (buf0 = even K-tiles, buf1 = odd). Linear LDS for global_load_lds;
// inverse-XOR swizzle on GLOBAL source; matching XOR on ds_read.
// Frag ds_reads are issued AFTER each phase's MFMA cluster, loading the NEXT
// phase's fragments into the same (dead) register sets -> the LDS pipe drains
// under the next MFMA cluster instead of serializing with it.
static __device__ __forceinline__ void stage_half(const u16* __restrict__ src, u16* dst,
                                                  int K, int sr, int sgc, int wave) {
  gld_lds16(src + (size_t)sr * K + sgc,       dst + wave * 1024);
  gld_lds16(src + (size_t)(sr + 8) * K + sgc, dst + wave * 1024 + 512);
}

static __device__ __forceinline__ void lda4(bf16x8 (&dst)[4][2], const u16* sAb,
                                            int mh, int wm, int lid, int c0) {
  #pragma unroll
  for (int i = 0; i < 4; ++i) {
    const u16* p = sAb + (mh * 128 + wm * 64 + i * 16 + lid) * 64;
    dst[i][0] = *(const bf16x8*)(p + c0);
    dst[i][1] = *(const bf16x8*)(p + (c0 ^ 32));
  }
}

static __device__ __forceinline__ void ldb2(bf16x8 (&dst)[2][2], const u16* sBb,
                                            int nh, int wn, int lid, int c0) {
  #pragma unroll
  for (int n = 0; n < 2; ++n) {
    const u16* p = sBb + (nh * 128 + wn * 32 + n * 16 + lid) * 64;
    dst[n][0] = *(const bf16x8*)(p + c0);
    dst[n][1] = *(const bf16x8*)(p + (c0 ^ 32));
  }
}

static __device__ __forceinline__ void quad16(f32x4 (&acc)[8][4], const bf16x8 (&af)[4][2],
                                              const bf16x8 (&bf)[2][2], int mh, int nh) {
  __builtin_amdgcn_s_setprio(1);
  #pragma unroll
  for (int i = 0; i < 4; ++i)
    #pragma unroll
    for (int n = 0; n < 2; ++n) {
      f32x4 c = acc[mh * 4 + i][nh * 2 + n];
      c = __builtin_amdgcn_mfma_f32_16x16x32_bf16(af[i][0], bf[n][0], c, 0, 0, 0);
      c = __builtin_amdgcn_mfma_f32_16x16x32_bf16(af[i][1], bf[n][1], c, 0, 0, 0);
      acc[mh * 4 + i][nh * 2 + n] = c;
    }
  __builtin_amdgcn_s_setprio(0);
}

#define VMW(n) asm volatile("s_waitcnt vmcnt(" #n ")" ::: "memory")
#define BAR8() __builtin_amdgcn_s_barrier()

// Stage issue ring per iter (2 loads each): P1:S1=b1.A1(kt1) P2:S2=b0.A0(kt2)
// P3:S3=b0.B0 P4:S4=b0.B1 P5:S5=b0.A1 P6:S6=b1.A0(kt3) P7:S7=b1.B0 P8:S8=b1.B1.
// Post-MFMA reads: P1:B1(T0)<-S4(prev) P2:A1(T0)<-S5(prev) P4:B0,A0(T1)<-S7,S6(prev)
// P5:B1(T1)<-S8(prev) P6:A1(T1)<-S1(cur) P8:B0,A0(T0')<-S3,S2(cur).
#define EIGHT_PHASE_LOOP(NITER)                                               \
  {                                                                           \
    STAGE_A(0,0,0); STAGE_B(0,0,0); STAGE_B(0,1,0); STAGE_A(0,1,0);           \
    STAGE_A(1,0,1); STAGE_B(1,0,1); STAGE_B(1,1,1);                           \
    VMW(6);                                                                   \
    BAR8();                                                                   \
    lda4(af, sA[0], 0, wm, lid, c0);   /* A0(T0) */                           \
    ldb2(bW, sB[0], 0, wn, lid, c0);   /* B0(T0) */                           \
    for (int I = 0; I < (NITER); ++I) {                                       \
      const bool more = (I + 1 < (NITER));                                    \
      const int kt1 = 2*I+1, kt2 = 2*I+2, kt3 = 2*I+3;                        \
      /* P1: T0 q(0,0); post-read B1(T0) */                                   \
      STAGE_A(1,1,kt1);                                                       \
      BAR8();                                                                 \
      quad16(acc, af, bW, 0, 0);                                              \
      ldb2(bX, sB[0], 1, wn, lid, c0);                                        \
      VMW(8);                                                                 \
      BAR8();                                                                 \
      /* P2: q(0,1); post-read A1(T0) */                                      \
      if (more) STAGE_A(0,0,kt2);                                             \
      BAR8();                                                                 \
      quad16(acc, af, bX, 0, 1);                                              \
      lda4(af, sA[0], 1, wm, lid, c0);                                        \
      BAR8();                                                                 \
      /* P3: q(1,1) */                                                        \
      if (more) STAGE_B(0,0,kt2);                                             \
      BAR8();                                                                 \
      quad16(acc, af, bX, 1, 1);                                              \
      if (more) { VMW(8); } else { VMW(4); }                                  \
      BAR8();                                                                 \
      /* P4: q(1,0); post-read B0(T1), A0(T1) */                              \
      if (more) STAGE_B(0,1,kt2);                                             \
      BAR8();                                                                 \
      quad16(acc, af, bW, 1, 0);                                              \
      ldb2(bW, sB[1], 0, wn, lid, c0);                                        \
      lda4(af, sA[1], 0, wm, lid, c0);                                        \
      if (more) { VMW(8); } else { VMW(2); }                                  \
      BAR8();                                                                 \
      /* P5: T1 q(0,0); post-read B1(T1) */                                   \
      if (more) STAGE_A(0,1,kt2);                                             \
      BAR8();                                                                 \
      quad16(acc, af, bW, 0, 0);                                              \
      ldb2(bX, sB[1], 1, wn, lid, c0);                                        \
      if (more) { VMW(8); } else { VMW(0); }                                  \
      BAR8();                                                                 \
      /* P6: q(0,1); post-read A1(T1) */                                      \
      if (more) STAGE_A(1,0,kt3);                                             \
      BAR8();                                                                 \
      quad16(acc, af, bX, 0, 1);                                              \
      lda4(af, sA[1], 1, wm, lid, c0);                                        \
      BAR8();                                                                 \
      /* P7: q(1,1) */                                                        \
      if (more) STAGE_B(1,0,kt3);                                             \
      BAR8();                                                                 \
      quad16(acc, af, bX, 1, 1);                                              \
      if (more) { VMW(8); }                                                   \
      BAR8();                                                                 \
      /* P8: q(1,0); post-read B0(T0'), A0(T0') */                            \
      if (more) STAGE_B(1,1,kt3);                                             \
      BAR8();                                                                 \
      quad16(acc, af, bW, 1, 0);                                              \
      if (more) {                                                             \
        ldb2(bW, sB[0], 0, wn, lid, c0);                                      \
        lda4(af, sA[0], 0, wm, lid, c0);                                      \
        VMW(8);                                                               \
      }                                                                       \
      BAR8();                                                                 \
    }                                                                         \
  }

// ================= ff1 GEMM + SwiGLU (256x(128val+128gate), BK=64, 8-phase) =================
__global__ __launch_bounds__(512, 2)
void gemm_ff1_swiglu_8p(const u16* __restrict__ A, const u16* __restrict__ BT,
                        u16* __restrict__ FF) {
  __shared__ __align__(16) u16 sA[2][256 * 64];   // 64 KB
  __shared__ __align__(16) u16 sB[2][256 * 64];   // 64 KB
  const int tid = threadIdx.x;
  const int wave = tid >> 6, lane = tid & 63;
  const int lid = lane & 15, quad = lane >> 4;
  const int wm = wave >> 2, wn = wave & 3;
  const int K = DIMM;

  // XCD-aware swizzle: nwg = 1024, 8 XCDs, 128 blocks each (bijective)
  int orig = blockIdx.y * 64 + blockIdx.x;
  int swz = (orig & 7) * 128 + (orig >> 3);
  const int row0 = (swz >> 6) * 256;
  const int n0 = (swz & 63) * 128;

  const int sr  = wave * 16 + (lane >> 3);           // stage row within half-tile
  const int sgc = (((lane & 7) ^ (lane >> 3)) << 3); // pre-swizzled source chunk (u16)
  const int c0  = ((quad ^ (lid & 7)) << 3);         // ds_read swizzled chunk (u16)

  f32x4 acc[8][4];
  #pragma unroll
  for (int i = 0; i < 8; ++i)
    #pragma unroll
    for (int j = 0; j < 4; ++j) { acc[i][j][0]=0.f; acc[i][j][1]=0.f; acc[i][j][2]=0.f; acc[i][j][3]=0.f; }
  bf16x8 af[4][2], bW[2][2], bX[2][2];

  #define STAGE_A(b, h, kt) stage_half(A  + (size_t)(row0 + (h)*128) * K + (kt)*64, &sA[b][(h)*8192], K, sr, sgc, wave)
  #define STAGE_B(b, h, kt) stage_half(BT + (size_t)((h) ? (FFH + n0) : n0) * K + (kt)*64, &sB[b][(h)*8192], K, sr, sgc, wave)

  EIGHT_PHASE_LOOP(K / 128)

  #undef STAGE_A
  #undef STAGE_B

  // ---- epilogue: SwiGLU (val = acc[..][0..1], gate = acc[..][2..3], same output col) ----
  #pragma unroll
  for (int mi = 0; mi < 8; ++mi) {
    const int row = row0 + (mi >> 2) * 128 + wm * 64 + (mi & 3) * 16 + quad * 4;
    #pragma unroll
    for (int n = 0; n < 2; ++n) {
      const int col = n0 + wn * 32 + n * 16 + lid;
      #pragma unroll
      for (int rg = 0; rg < 4; ++rg) {
        float vv = acc[mi][n][rg];
        float gg = acc[mi][2 + n][rg];
        float sig = 1.0f / (1.0f + fast_exp2(-gg * LOG2E));
        FF[(size_t)(row + rg) * FFH + col] = f2bf(vv * gg * sig);
      }
    }
  }
}

// ================= ff2 GEMM (256x256, BK=64, 8-phase, split-K=2) =================
// Grid 8 x 16 x 2 = 256 blocks (1 round on 256 CUs). ks=0 -> out, ks=1 -> tmp;
// the attn-out GEMM epilogue adds tmp back (out += attnproj + tmp).
__global__ __launch_bounds__(512, 2)
void gemm_ff2_8p(const u16* __restrict__ A, const u16* __restrict__ BT,
                 float* __restrict__ out0, float* __restrict__ out1) {
  __shared__ __align__(16) u16 sA[2][256 * 64];
  __shared__ __align__(16) u16 sB[2][256 * 64];
  const int tid = threadIdx.x;
  const int wave = tid >> 6, lane = tid & 63;
  const int lid = lane & 15, quad = lane >> 4;
  const int wm = wave >> 2, wn = wave & 3;
  const int K = FFH;  // row stride (full K)

  // XCD swizzle over 256 blocks: 32 per XCD = 2 row-panels x 8 n-panels x 2 ks
  int orig = (blockIdx.z * 16 + blockIdx.y) * 8 + blockIdx.x;
  int swz = (orig & 7) * 32 + (orig >> 3);
  const int n0   = (swz & 7) * 256;
  const int ks   = (swz >> 3) & 1;
  const int row0 = (swz >> 4) * 256;

  const u16* Ab = A  + ks * 4096;   // K-half column offset
  const u16* Bb = BT + ks * 4096;

  const int sr  = wave * 16 + (lane >> 3);
  const int sgc = (((lane & 7) ^ (lane >> 3)) << 3);
  const int c0  = ((quad ^ (lid & 7)) << 3);

  f32x4 acc[8][4];
  #pragma unroll
  for (int i = 0; i < 8; ++i)
    #pragma unroll
    for (int j = 0; j < 4; ++j) { acc[i][j][0]=0.f; acc[i][j][1]=0.f; acc[i][j][2]=0.f; acc[i][j][3]=0.f; }
  bf16x8 af[4][2], bW[2][2], bX[2][2];

  #define STAGE_A(b, h, kt) stage_half(Ab + (size_t)(row0 + (h)*128) * K + (kt)*64, &sA[b][(h)*8192], K, sr, sgc, wave)
  #define STAGE_B(b, h, kt) stage_half(Bb + (size_t)(n0 + (h)*128) * K + (kt)*64,  &sB[b][(h)*8192], K, sr, sgc, wave)

  EIGHT_PHASE_LOOP(32)   // K-half 4096 / 128

  #undef STAGE_A
  #undef STAGE_B

  float* dst = ks ? out1 : out0;
  #pragma unroll
  for (int mi = 0; mi < 8; ++mi) {
    const int row = row0 + (mi >> 2) * 128 + wm * 64 + (mi & 3) * 16 + quad * 4;
    #pragma unroll
    for (int j = 0; j < 4; ++j) {
      const int col = n0 + (j >> 1) * 128 + wn * 32 + (j & 1) * 16 + lid;
      #pragma unroll
      for (int rg = 0; rg < 4; ++rg)
        dst[(size_t)(row + rg) * DIMM + col] = acc[mi][j][rg];
    }
  }
}

// ---------------- flash attention v3: 16 q-rows/wave, KVBLK=64, 2 blocks/CU ----------------
// Block: 4 waves x 16 q-rows = 64-row tile; T-tiles of 64 rows (TT=0..31), paired
// (pair, 31-pair) for causal balance -> grid 16 x 32 = 512 blocks = 2/CU resident
// (LDS 41 KB, VGPR <= 256 via launch_bounds). Cross-block overlap hides MFMA dep
// chains + serial softmax VALU that were fully exposed at 1 wave/SIMD.
__global__ __launch_bounds__(256, 2)
void attn_k3(const u16* __restrict__ qws, const u16* __restrict__ kvws,
             const u16* __restrict__ kvt, u16* __restrict__ attnws) {
  __shared__ __align__(16) u16 kvls[64 * 128];    // 16 KB: K/V rows j, 128 d-cols
  __shared__ __align__(16) u16 kvtls[128 * 64];   // 16 KB: V^T rows d, 64 j-cols
  __shared__ __align__(16) u16 plds[4][16][72];   // 9 KB, row stride 144 B (16B mult)
  const int tid = threadIdx.x;
  const int wave = tid >> 6, lane = tid & 63;
  const int lid = lane & 15, quad = lane >> 4;
  const int hb = blockIdx.y;
  const int h = hb & (NH - 1), b = hb >> 4;
  const int pair = blockIdx.x;                     // 0..15
  const float slope2 = fast_exp2(-0.5f * (float)(h + 1)) * LOG2E;
  const float scale2 = 0.08838834764831845f * LOG2E;   // 1/sqrt(128) * log2(e)
  const float NEG = -__builtin_inff();

  const u16* kvb  = kvws + (size_t)b * SEQ * DH;
  const u16* kvtb = kvt  + (size_t)b * DH * SEQ;

  #pragma unroll 1
  for (int tt = 0; tt < 2; tt++) {
    const int TT = tt ? (31 - pair) : pair;
    const int rw = TT * 64 + wave * 16;            // wave's 16-row strip base

    bf16x8 qf[4];
    #pragma unroll
    for (int ks = 0; ks < 4; ks++)
      qf[ks] = *(const bf16x8*)(qws + (size_t)(b * SEQ + rw + lid) * DIMM
                                 + h * DH + ks * 32 + quad * 8);
    float srow[4];
    #pragma unroll
    for (int rg = 0; rg < 4; rg++)
      srow[rg] = slope2 * (float)(rw + quad * 4 + rg);

    f32x4 o[8];
    #pragma unroll
    for (int nd = 0; nd < 8; nd++) { o[nd][0]=0.f; o[nd][1]=0.f; o[nd][2]=0.f; o[nd][3]=0.f; }
    float m2[4], l[4];
    #pragma unroll
    for (int rg = 0; rg < 4; rg++) { m2[rg] = NEG; l[rg] = 0.f; }

    const int njt = TT + 1;
    #pragma unroll 1
    for (int jt = 0; jt < njt; jt++) {
      const int j0 = jt * 64;
      __syncthreads();                              // prev tile LDS reads complete
      {
        const int c16 = lane & 15, r16 = lane >> 4; // kvls: 16 lanes/row (128 u16)
        const int c8  = lane & 7,  r8  = lane >> 3; // kvtls: 8 lanes/row (64 u16)
        #pragma unroll
        for (int it = 0; it < 4; it++) {
          const int r  = wave * 16 + it * 4 + r16;
          const int gc = c16 ^ (r & 15);
          gld_lds16(kvb + (size_t)(j0 + r) * DH + gc * 8, kvls + (wave * 16 + it * 4) * 128);
          const int r2  = wave * 32 + it * 8 + r8;
          const int gc2 = c8 ^ (r2 & 7);
          gld_lds16(kvtb + (size_t)r2 * SEQ + j0 + gc2 * 8, kvtls + (wave * 32 + it * 8) * 64);
        }
      }
      __syncthreads();                              // staging drained

      const int nbmax = min(4, ((rw + 15 - j0) >> 4) + 1);   // wave-uniform
      const int ks2max = (nbmax + 1) >> 1;

      float pvv[4][4];
      float mt[4];
      #pragma unroll
      for (int rg = 0; rg < 4; rg++) mt[rg] = NEG;

      #pragma unroll
      for (int nb = 0; nb < 4; nb++) {
        if (nb < nbmax) {
          bf16x8 bk[4];
          #pragma unroll
          for (int ks = 0; ks < 4; ks++)
            bk[ks] = *(const bf16x8*)(kvls + (nb * 16 + lid) * 128 + (((ks * 4 + quad) ^ lid) << 3));
          f32x4 s;
          s[0]=0.f; s[1]=0.f; s[2]=0.f; s[3]=0.f;
          #pragma unroll
          for (int ks = 0; ks < 4; ks++)
            s = __builtin_amdgcn_mfma_f32_16x16x32_bf16(qf[ks], bk[ks], s, 0, 0, 0);
          const int jl = j0 + nb * 16 + lid;
          const float sj = slope2 * (float)jl;
          #pragma unroll
          for (int rg = 0; rg < 4; rg++) {
            const int row0r = rw + quad * 4 + rg;
            float e = fmaf(s[rg], scale2, sj) - srow[rg];
            e = (jl <= row0r) ? e : NEG;
            pvv[nb][rg] = e;
            mt[rg] = fmaxf(mt[rg], e);
          }
        }
      }

      float alpha[4];
      #pragma unroll
      for (int rg = 0; rg < 4; rg++) {
        float m = mt[rg];
        m = fmaxf(m, __shfl_xor(m, 1));
        m = fmaxf(m, __shfl_xor(m, 2));
        m = fmaxf(m, __shfl_xor(m, 4));
        m = fmaxf(m, __shfl_xor(m, 8));
        float mn = fmaxf(m2[rg], m);
        alpha[rg] = fast_exp2(m2[rg] - mn);
        m2[rg] = mn;
      }

      float rs[4];
      #pragma unroll
      for (int rg = 0; rg < 4; rg++) rs[rg] = 0.f;
      #pragma unroll
      for (int nb = 0; nb < 4; nb++) {
        if (nb < nbmax) {
          #pragma unroll
          for (int rg = 0; rg < 4; rg++) {
            float p = fast_exp2(pvv[nb][rg] - m2[rg]);
            rs[rg] += p;
            plds[wave][quad * 4 + rg][nb * 16 + lid] = f2bf(p);
          }
        }
      }
      if (nbmax & 1) {                               // zero pad strip (odd nb-count)
        #pragma unroll
        for (int rg = 0; rg < 4; rg++)
          plds[wave][quad * 4 + rg][nbmax * 16 + lid] = 0;
      }

      #pragma unroll
      for (int rg = 0; rg < 4; rg++) {
        float r = rs[rg];
        r += __shfl_xor(r, 1);
        r += __shfl_xor(r, 2);
        r += __shfl_xor(r, 4);
        r += __shfl_xor(r, 8);
        l[rg] = l[rg] * alpha[rg] + r;
      }
      #pragma unroll
      for (int nd = 0; nd < 8; nd++)
        #pragma unroll
        for (int rg = 0; rg < 4; rg++) o[nd][rg] *= alpha[rg];

      asm volatile("s_waitcnt lgkmcnt(0)" ::: "memory");   // plds writes visible
      #pragma unroll
      for (int ks2 = 0; ks2 < 2; ks2++) {
        if (ks2 < ks2max) {
          bf16x8 pa = *(const bf16x8*)&plds[wave][lid][ks2 * 32 + quad * 8];
          #pragma unroll
          for (int nd = 0; nd < 8; nd++) {
            bf16x8 bv = *(const bf16x8*)(kvtls + (nd * 16 + lid) * 64
                                          + (((ks2 * 4 + quad) ^ (lid & 7)) << 3));
            o[nd] = __builtin_amdgcn_mfma_f32_16x16x32_bf16(pa, bv, o[nd], 0, 0, 0);
          }
        }
      }
    } // jt

    float inv[4];
    #pragma unroll
    for (int rg = 0; rg < 4; rg++) inv[rg] = 1.0f / l[rg];
    #pragma unroll
    for (int nd = 0; nd < 8; nd++)
      #pragma unroll
      for (int rg = 0; rg < 4; rg++) {
        int row = rw + quad * 4 + rg;
        attnws[(size_t)(b * SEQ + row) * DIMM + h * DH + nd * 16 + lid] =
            f2bf(o[nd][rg] * inv[rg]);
      }
  } // tt
}

// ---------------- launcher ----------------
extern "C" void kernel_launch(void* const* d_in, const int* in_sizes, int n_in,
                              void* d_out, int out_size, void* d_ws, size_t ws_size,
                              hipStream_t stream) {
  (void)in_sizes; (void)n_in; (void)out_size; (void)ws_size;
  const float* x     = (const float*)d_in[0];
  const float* g     = (const float*)d_in[1];
  const float* w_qkv = (const float*)d_in[2];
  const float* w_ao  = (const float*)d_in[3];
  const float* w_ff1 = (const float*)d_in[4];
  const float* w_ff2 = (const float*)d_in[5];
  float* out = (float*)d_out;

  u16* ws = (u16*)d_ws;
  u16* xn     = ws;                   // 4096x2048
  u16* wTqkv  = xn     + 8388608;     // 2176x2048
  u16* wTattn = wTqkv  + 4456448;     // 2048x2048
  u16* wTff1  = wTattn + 4194304;     // 16384x2048
  u16* wTff2  = wTff1  + 33554432;    // 2048x8192
  u16* ffin   = wTff2  + 16777216;    // 4096x8192
  u16* qws    = ffin   + 33554432;    // 4096x2048
  u16* kvws   = qws    + 8388608;     // 4096x128
  u16* kvtws  = kvws   + 524288;      // 2 x (128x2048)
  u16* attnws = kvtws  + 524288;      // 4096x2048
  float* tmpf = (float*)wTff1;        // 4096x2048 fp32 (dead after ff1, 64MB region)

  transpose_to_bf16<float><<<dim3(QKVN/64, DIMM/64), 256, 0, stream>>>(w_qkv, wTqkv, DIMM, QKVN);
  transpose_to_bf16<float><<<dim3(DIMM/64, DIMM/64), 256, 0, stream>>>(w_ao, wTattn, DIMM, DIMM);
  transpose_to_bf16<float><<<dim3((2*FFH)/64, DIMM/64), 256, 0, stream>>>(w_ff1, wTff1, DIMM, 2*FFH);
  transpose_to_bf16<float><<<dim3(DIMM/64, FFH/64), 256, 0, stream>>>(w_ff2, wTff2, FFH, DIMM);

  rmsnorm_k<<<ROWS, 256, 0, stream>>>(x, g, xn);

  gemm_bf16<0><<<dim3(QKVN/128, ROWS/128), 256, 0, stream>>>(xn, wTqkv, DIMM, nullptr, qws, kvws, nullptr);

  transpose_to_bf16<u16><<<dim3(DH/64, SEQ/64), 256, 0, stream>>>(kvws, kvtws, SEQ, DH);
  transpose_to_bf16<u16><<<dim3(DH/64, SEQ/64), 256, 0, stream>>>(kvws + (size_t)SEQ*DH, kvtws + (size_t)DH*SEQ, SEQ, DH);

  attn_k3<<<dim3(16, NH*BATCH), 256, 0, stream>>>(qws, kvws, kvtws, attnws);

  gemm_ff1_swiglu_8p<<<dim3(FFH/128, ROWS/256), 512, 0, stream>>>(xn, wTff1, ffin);
  gemm_ff2_8p<<<dim3(8, 16, 2), 512, 0, stream>>>(ffin, wTff2, out, tmpf);

  gemm_bf16<3><<<dim3(DIMM/128, ROWS/128), 256, 0, stream>>>(attnws, wTattn, DIMM, out, nullptr, nullptr, tmpf);
}